// Round 6
// baseline (332.625 us; speedup 1.0000x reference)
//
#include <hip/hip_runtime.h>

// Problem constants
#define B_SZ   64
#define IC_N   128
#define OC_N   128
#define OUT_D  1024
#define L_N    2048

typedef __attribute__((ext_vector_type(8))) __bf16 bf16x8;
typedef __attribute__((ext_vector_type(4))) float  f32x4;

// RNE fp32->bf16, packed pair (lo in low 16 bits).
__device__ __forceinline__ unsigned pack2bf(float lo, float hi) {
    unsigned ul = __builtin_bit_cast(unsigned, lo);
    unsigned uh = __builtin_bit_cast(unsigned, hi);
    ul += 0x7fffu + ((ul >> 16) & 1u);
    uh += 0x7fffu + ((uh >> 16) & 1u);
    return (ul >> 16) | (uh & 0xffff0000u);
}

// ======================= FUSED single-pass kernel ===========================
// Round-6: identical to round-3 (best measured, 127 us dispatch) except the
// block->d mapping and chunk alignment — a single-variable test of the
// address-footprint theory:
//   OLD: dg = (bid&7)*32 + (bid>>3): each XCD's 32 blocks read a contiguous
//        1 KB window of every 8 KB row -> only ~1/8 of each DRAM page/channel
//        set touched per instant; every structure with this signature pinned
//        at 1.0-2.0 TB/s regardless of depth (r5: VGPR=108 proved 24 loads
//        in flight, rate unchanged) or occupancy (r4: 2x waves, unchanged).
//   NEW: dg = (bid>>3)*8 + (bid&7): XCD x's blocks sit at 256 B spacing
//        spanning the FULL row; the 8 XCDs interleave at 32 B offsets.
//        GPU-wide instantaneous coverage of each touched row = 100% ->
//        full DRAM-page consumption per activation, all channels busy.
//   Chunk stagger removed: page completion needs the 256 blocks' touches
//   time-aligned on the same ic-chunk.
// Everything else (LDS dbuf, one barrier/chunk, fragment maps, epilogue)
// is byte-identical to the verified round-3 kernel.
__global__ __launch_bounds__(512, 2)
void lc1d_fused(const float* __restrict__ x, const float* __restrict__ w,
                float* __restrict__ out) {
    __shared__ __align__(16) unsigned smem[2][12288];   // 2 x 48 KB

    const int bid = blockIdx.x;
    const int dg  = (bid >> 3) * 8 + (bid & 7);      // bijection on [0,256)
    const int t = threadIdx.x, wv = t >> 6, lane = t & 63;
    const int col = lane & 15, quad = lane >> 4;

    // staging coords
    const int j   = t & 1;
    const int icl = (t >> 1) & 15;
    const int rb  = t >> 5;                          // 0..15

    const size_t rowoff  = ((size_t)rb * IC_N + icl) * L_N + (size_t)dg * 8 + 4 * j;
    const float* xp = x + rowoff;
    const float* wp = w + rowoff;
    const size_t RSTRIDE = (size_t)16 * IC_N * L_N;  // +16 rows (b or oc)
    const size_t CSTRIDE = (size_t)16 * L_N;         // +16 ic (next chunk)

    // compute coords
    const int dl = wv & 3;
    const int xoff = dl * 1024 + col * 16 + quad * 4;
    const int woff = 4096 + dl * 2048 + ((wv >> 2) * 64 + col) * 16 + quad * 4;

    f32x4 acc[4][4];
#pragma unroll
    for (int mt = 0; mt < 4; ++mt)
#pragma unroll
        for (int nt = 0; nt < 4; ++nt)
            acc[mt][nt] = (f32x4){0.f, 0.f, 0.f, 0.f};

    float4 xvA[4], wvA[8], xvB[4], wvB[8];

    auto load_ab = [&](float4* XV, float4* WV, int c) {
        const float* xq = xp + (size_t)c * CSTRIDE;
        const float* wq = wp + (size_t)c * CSTRIDE;
#pragma unroll
        for (int r = 0; r < 4; ++r) XV[r] = *(const float4*)(xq + (size_t)r * RSTRIDE);
#pragma unroll
        for (int r = 0; r < 8; ++r) WV[r] = *(const float4*)(wq + (size_t)r * RSTRIDE);
    };

    auto store_slab = [&](int buf, const float4* XV, const float4* WV) {
        unsigned* Xs = smem[buf];
        unsigned* Ws = smem[buf] + 4096;
#pragma unroll
        for (int r = 0; r < 4; ++r) {
            const int row = (rb + 16 * r) * 16 + icl;
            Xs[(2 * j) * 1024 + row]     = pack2bf(XV[r].x, XV[r].y);
            Xs[(2 * j + 1) * 1024 + row] = pack2bf(XV[r].z, XV[r].w);
        }
#pragma unroll
        for (int r = 0; r < 8; ++r) {
            const int row = (rb + 16 * r) * 16 + icl;
            Ws[(2 * j) * 2048 + row]     = pack2bf(WV[r].x, WV[r].y);
            Ws[(2 * j + 1) * 2048 + row] = pack2bf(WV[r].z, WV[r].w);
        }
    };

    auto compute = [&](int buf) {
        const unsigned* base = smem[buf];
        bf16x8 a[4], b[4];
#pragma unroll
        for (int mt = 0; mt < 4; ++mt)
            a[mt] = __builtin_bit_cast(bf16x8, *(const uint4*)(base + xoff + mt * 256));
#pragma unroll
        for (int nt = 0; nt < 4; ++nt)
            b[nt] = __builtin_bit_cast(bf16x8, *(const uint4*)(base + woff + nt * 256));
#pragma unroll
        for (int mt = 0; mt < 4; ++mt)
#pragma unroll
            for (int nt = 0; nt < 4; ++nt)
                acc[mt][nt] = __builtin_amdgcn_mfma_f32_16x16x32_bf16(
                    a[mt], b[nt], acc[mt][nt], 0, 0, 0);
    };

    // prologue: 2 chunks in flight
    load_ab(xvA, wvA, 0);
    load_ab(xvB, wvB, 1);

#pragma unroll
    for (int cc = 0; cc < 8; cc += 2) {
        // even chunk -> buf0 (consumes A; A regs then refilled for cc+2)
        store_slab(0, xvA, wvA);
        __syncthreads();
        if (cc + 2 < 8) load_ab(xvA, wvA, cc + 2);
        compute(0);

        // odd chunk -> buf1
        store_slab(1, xvB, wvB);
        __syncthreads();
        if (cc + 3 < 8) load_ab(xvB, wvB, cc + 3);
        compute(1);
    }

    // ---- epilogue: LDS transpose (reuse smem, 40 KB) -> float4 d-run stores -
    const float scale = 0.088388347648318447f;   // 1/sqrt(128)
    float* ep = (float*)smem;
    const int nh2 = wv >> 2;
#pragma unroll
    for (int r = 0; r < 4; ++r) {                // b-chunk of 16 (= mt tile r)
        __syncthreads();                         // prior smem reads done
#pragma unroll
        for (int nt = 0; nt < 4; ++nt)
#pragma unroll
            for (int reg = 0; reg < 4; ++reg) {
                const int b_l = 4 * quad + reg;
                const int o   = nh2 * 64 + 16 * nt + col;
                ep[(b_l * 128 + o) * 5 + dl] = acc[r][nt][reg] * scale;
            }
        __syncthreads();
#pragma unroll
        for (int pi = 0; pi < 4; ++pi) {
            const int P = t + 512 * pi;          // (b_l, o) pair, 0..2047
            const int b_l = P >> 7, o = P & 127;
            const float* s = &ep[(size_t)P * 5];
            float4 v;
            v.x = s[0]; v.y = s[1]; v.z = s[2]; v.w = s[3];
            *(float4*)&out[(size_t)((16 * r + b_l) * OC_N + o) * OUT_D + dg * 4] = v;
        }
    }
}

// ================================ launch ====================================
extern "C" void kernel_launch(void* const* d_in, const int* in_sizes, int n_in,
                              void* d_out, int out_size, void* d_ws, size_t ws_size,
                              hipStream_t stream) {
    const float* x = (const float*)d_in[0];
    const float* w = (const float*)d_in[1];
    float* out     = (float*)d_out;
    hipLaunchKernelGGL(lc1d_fused, dim3(256), dim3(512), 0, stream, x, w, out);
}